// Round 1
// baseline (209.889 us; speedup 1.0000x reference)
//
#include <hip/hip_runtime.h>
#include <stdint.h>

// HashedEmbeddingBag: out[b][d] = sum_{l<50} w[ ((idx[b][l]*A + d*B) % P) % W ]
// B=16384 bags, L=50, E=64 dims, W=1e6 (4MB table, L2-resident).
// Mapping: lane -> dim d (wave64 == EMB_DIM), wave -> bag.
//   hb[d]   = d*B % P          (once per lane)
//   mA(b,l) = idx*A % P        (wave-uniform, once per (bag,l))
//   h       = (mA + hb) mod P, then mod W (magic-mul)
// Gathers are inherently uncoalesced (hash is uniform over 4MB) -> L2-request bound.

#define BAG_LEN 50
#define EMB_DIM 64
#define WEIGHT_SIZE 1000000ULL
#define HASH_A 9824516537ULL
#define HASH_B 57857966300227ULL
#define HASH_P 117130198221199ULL

__global__ __launch_bounds__(256) void heb_kernel(
    const float* __restrict__ w,
    const int* __restrict__ idx,
    float* __restrict__ out,
    int num_bags)
{
    const int lane = threadIdx.x & 63;
    const int wid  = threadIdx.x >> 6;
    const int bag  = blockIdx.x * 4 + wid;
    if (bag >= num_bags) return;

    // per-lane (per-dim) hash offset, computed once
    const uint64_t hb = ((uint64_t)lane * HASH_B) % HASH_P;

    const int* bag_idx = idx + bag * BAG_LEN;

    float acc = 0.0f;
#pragma unroll
    for (int l = 0; l < BAG_LEN; ++l) {
        const uint64_t i  = (uint64_t)(uint32_t)bag_idx[l];      // wave-uniform load
        uint64_t t = (i * HASH_A) % HASH_P;                      // < P
        t += hb;                                                 // < 2P < 2^48
        if (t >= HASH_P) t -= HASH_P;
        const uint32_t h = (uint32_t)(t % WEIGHT_SIZE);          // magic-mul mod 1e6
        acc += w[h];                                             // 4B gather, L2-resident
    }

    out[bag * EMB_DIM + lane] = acc;                             // coalesced
}

extern "C" void kernel_launch(void* const* d_in, const int* in_sizes, int n_in,
                              void* d_out, int out_size, void* d_ws, size_t ws_size,
                              hipStream_t stream) {
    const float* w   = (const float*)d_in[0];   // hashed_weight, 1e6 f32
    const int*   idx = (const int*)d_in[1];     // indices, 16384*50 int32
    float*       out = (float*)d_out;           // 16384*64 f32

    const int num_bags = out_size / EMB_DIM;    // 16384
    const int bags_per_block = 4;               // 256 threads = 4 waves
    const int grid = (num_bags + bags_per_block - 1) / bags_per_block;

    heb_kernel<<<grid, 256, 0, stream>>>(w, idx, out, num_bags);
}

// Round 2
// 207.083 us; speedup vs baseline: 1.0135x; 1.0135x over previous
//
#include <hip/hip_runtime.h>
#include <stdint.h>

// HashedEmbeddingBag: out[b][d] = sum_{l<50} w[ ((idx[b][l]*A + d*B) % P) % W ]
// B=16384 bags, L=50, E=64 dims, W=1e6 (4MB table, L2-resident).
// Mapping: lane -> dim d (wave64 == EMB_DIM), wave -> bag (readfirstlane'd so
// the compiler scalarizes index loads -> s_load, and the 64-bit hash -> SALU).
//
// Per-lane mod decomposition (avoids per-lane 64-bit magic-mod):
//   t  = mA + hb           (mA = i*A mod P  [scalar], hb = d*B mod P [per-lane])
//   v  = t - (t>=P ? P:0);  h = v mod W
//   t mod W  = (mA mod W + hb mod W) mod W
//   (t-P) mod W = (mA mod W + hb mod W + (W - P mod W)) mod W
//   t>=P  <=>  hb >= P - mA        (one v_cmp_ge_u64 vs scalar pair)

#define BAG_LEN 50
#define EMB_DIM 64
#define WEIGHT_SIZE 1000000u
#define HASH_A 9824516537ULL
#define HASH_B 57857966300227ULL
#define HASH_P 117130198221199ULL
#define W_MINUS_PMODW 778801u   // WEIGHT_SIZE - (HASH_P % WEIGHT_SIZE=221199)

__global__ __launch_bounds__(256, 8) void heb_kernel(
    const float* __restrict__ w,
    const int* __restrict__ idx,
    float* __restrict__ out,
    int num_bags)
{
    const int lane = threadIdx.x & 63;
    const int wid  = threadIdx.x >> 6;
    int bag = blockIdx.x * 4 + wid;
    bag = __builtin_amdgcn_readfirstlane(bag);   // wave-uniform by construction
    if (bag >= num_bags) return;

    // per-lane (per-dim) hash offset, computed once
    const uint64_t hb     = ((uint64_t)lane * HASH_B) % HASH_P;
    const uint32_t hb_mod = (uint32_t)(hb % (uint64_t)WEIGHT_SIZE);

    const int* bag_idx = idx + bag * BAG_LEN;    // uniform -> s_load path

    float acc0 = 0.f, acc1 = 0.f;

#pragma unroll
    for (int l0 = 0; l0 < BAG_LEN; l0 += 10) {
        uint32_t off[10];
#pragma unroll
        for (int j = 0; j < 10; ++j) {
            const uint32_t i  = (uint32_t)bag_idx[l0 + j];               // s_load
            const uint64_t mA = ((uint64_t)i * HASH_A) % HASH_P;         // SALU magic-mod
            const uint32_t aS = (uint32_t)(mA % (uint64_t)WEIGHT_SIZE);  // SALU
            const uint64_t Pm = HASH_P - mA;                             // SALU

            uint32_t r = aS + hb_mod;                    // VALU, sgpr operand
            if (hb >= Pm) r += W_MINUS_PMODW;            // v_cmp_ge_u64 + cndmask+add
            if (r >= 2u * WEIGHT_SIZE) r -= 2u * WEIGHT_SIZE;
            if (r >= WEIGHT_SIZE)      r -= WEIGHT_SIZE;
            off[j] = r;
        }
        float v[10];
#pragma unroll
        for (int j = 0; j < 10; ++j) v[j] = w[off[j]];   // 10 gathers in flight
#pragma unroll
        for (int j = 0; j < 10; ++j) { if (j & 1) acc1 += v[j]; else acc0 += v[j]; }
    }

    out[bag * EMB_DIM + lane] = acc0 + acc1;             // coalesced
}

extern "C" void kernel_launch(void* const* d_in, const int* in_sizes, int n_in,
                              void* d_out, int out_size, void* d_ws, size_t ws_size,
                              hipStream_t stream) {
    const float* w   = (const float*)d_in[0];   // hashed_weight, 1e6 f32
    const int*   idx = (const int*)d_in[1];     // indices, 16384*50 int32
    float*       out = (float*)d_out;           // 16384*64 f32

    const int num_bags = out_size / EMB_DIM;    // 16384
    const int bags_per_block = 4;               // 256 threads = 4 waves
    const int grid = (num_bags + bags_per_block - 1) / bags_per_block;

    heb_kernel<<<grid, 256, 0, stream>>>(w, idx, out, num_bags);
}